// Round 7
// baseline (230.886 us; speedup 1.0000x reference)
//
#include <hip/hip_runtime.h>

// PermuteWeightSharing: out[row, s*16+k] = x[row, ppos[s]*16+k] - x[row, pneg[s]*16+k]
// row = (b,o,i) flattened, 256 floats per row = 16 slots x 16 floats = 64 float4.
//
// v8: zero-preamble. All prior variants (77-87 us, 2.4-2.5 TB/s) shared a
// serial block preamble: Ppos/Pneg loads -> LDS decode -> __syncthreads,
// which must retire before any x-load can be addressed. Counters (v7:
// occ 63%, VALU 6%, 82 KB/CU statically in flight vs ~9 KB needed) say the
// kernel is duty-cycle-bound, not capacity-bound: threads hold x-loads only
// ~half their lifetime. Here the x-loads are sequential (permutation-
// independent, proven cost-equal in v5) and issue as the FIRST instructions;
// the permutation is decoded per-wave fully in-register (lane l loads
// float4 #l of each 16x16 matrix, 3 ballots encode the one-hot position) --
// no LDS, no barrier, decode latency overlaps x-load latency. Permutation
// applied post-load via ds_bpermute, plain stores.

#define NSLOTS 16

typedef float fvec4 __attribute__((ext_vector_type(4)));

__device__ inline fvec4 lane_gather(fvec4 a, int byte_addr)
{
    fvec4 r;
    r.x = __int_as_float(__builtin_amdgcn_ds_bpermute(byte_addr, __float_as_int(a.x)));
    r.y = __int_as_float(__builtin_amdgcn_ds_bpermute(byte_addr, __float_as_int(a.y)));
    r.z = __int_as_float(__builtin_amdgcn_ds_bpermute(byte_addr, __float_as_int(a.z)));
    r.w = __int_as_float(__builtin_amdgcn_ds_bpermute(byte_addr, __float_as_int(a.w)));
    return r;
}

// Wave-cooperative one-hot decode: lane l holds float4 #l of a 16x16
// row-major perm matrix (row = l>>2, cols (l&3)*4..+3). Returns, for this
// lane's `slot`, the hot column of row `slot` -- i.e. perm[slot].
__device__ inline int decode_col(const fvec4 pr, int slot)
{
    int  h    = 0;
    bool pres = false;
    if (pr.x > 0.5f) { h = 0; pres = true; }
    if (pr.y > 0.5f) { h = 1; pres = true; }
    if (pr.z > 0.5f) { h = 2; pres = true; }
    if (pr.w > 0.5f) { h = 3; pres = true; }
    const unsigned long long bp = __ballot(pres);     // which 4-float chunk is hot
    const unsigned long long b0 = __ballot(h & 1);    // low bit of within-chunk idx
    const unsigned long long b1 = __ballot(h >> 1);   // high bit
    const int nib = (int)((bp >> (slot * 4)) & 0xFull);      // 4 chunks of my row
    const int cl  = slot * 4 + __builtin_ctz(nib);           // hot chunk's lane
    const int hh  = (int)((b0 >> cl) & 1ull) | ((int)((b1 >> cl) & 1ull) << 1);
    return ((cl & 3) << 2) | hh;                             // col in [0,16)
}

__global__ __launch_bounds__(256, 8) void permute_ws_kernel(
    const fvec4* __restrict__ x,
    const float* __restrict__ Ppos,
    const float* __restrict__ Pneg,
    fvec4* __restrict__ out,
    int total_v4)
{
    const int t    = threadIdx.x;
    const int lane = t & 63;
    const int i0   = blockIdx.x * 1024 + t;   // 4 positions: +0,+256,+512,+768

    const bool full = (i0 + 768 < total_v4);

    // ---- x loads FIRST: sequential, permutation-independent ----
    fvec4 a0, a1, a2, a3;
    if (full) {
        a0 = x[i0 +   0];
        a1 = x[i0 + 256];
        a2 = x[i0 + 512];
        a3 = x[i0 + 768];
    }

    // ---- in-register decode (overlaps x-load latency; no LDS/barrier) ----
    const fvec4 prp = ((const fvec4*)Ppos)[lane];   // 64 float4 = whole matrix
    const fvec4 prn = ((const fvec4*)Pneg)[lane];
    const int slot = lane >> 2;
    const int k4   = lane & 3;
    const int colp = decode_col(prp, slot);
    const int coln = decode_col(prn, slot);
    // lane holding input float4 (4*col + k4); bpermute addr = src_lane*4
    const int bpa = (((colp << 2) | k4) << 2);
    const int bna = (((coln << 2) | k4) << 2);

    if (full) {
        out[i0 +   0] = lane_gather(a0, bpa) - lane_gather(a0, bna);
        out[i0 + 256] = lane_gather(a1, bpa) - lane_gather(a1, bna);
        out[i0 + 512] = lane_gather(a2, bpa) - lane_gather(a2, bna);
        out[i0 + 768] = lane_gather(a3, bpa) - lane_gather(a3, bna);
    } else {
        // Cold tail (unused when total_v4 % 1024 == 0): scattered gather.
        #pragma unroll
        for (int j = 0; j < 4; ++j) {
            const int i = i0 + 256 * j;
            if (i < total_v4) {
                const fvec4 a = x[i - lane + ((colp << 2) | k4)];
                const fvec4 b = x[i - lane + ((coln << 2) | k4)];
                out[i] = a - b;
            }
        }
    }
}

extern "C" void kernel_launch(void* const* d_in, const int* in_sizes, int n_in,
                              void* d_out, int out_size, void* d_ws, size_t ws_size,
                              hipStream_t stream)
{
    const fvec4* x    = (const fvec4*)d_in[0];
    const float* Ppos = (const float*)d_in[1];
    const float* Pneg = (const float*)d_in[2];
    fvec4*       out  = (fvec4*)d_out;

    const int total_v4 = out_size / 4;   // 33,554,432 / 4 = 8,388,608

    const int block = 256;
    // Each block covers 1024 float4 (16 rows, 4 per thread): 8192 blocks.
    const int grid = (total_v4 + 1023) / 1024;

    permute_ws_kernel<<<grid, block, 0, stream>>>(x, Ppos, Pneg, out, total_v4);
}

// Round 8
// 219.362 us; speedup vs baseline: 1.0525x; 1.0525x over previous
//
#include <hip/hip_runtime.h>

// PermuteWeightSharing: out[row, s*16+k] = x[row, ppos[s]*16+k] - x[row, pneg[s]*16+k]
// row = (b,o,i) flattened, 256 floats per row = 16 slots x 16 floats = 64 float4.
//
// v9 = v0 geometry (32768 blocks, 1 position/thread -- best measured, ~70us)
//    + v8 zero-preamble duty-cycle fix (x-load is the FIRST instruction,
//      permutation decoded per-wave in-register via ballots, applied with
//      ds_bpermute; no LDS, no __syncthreads).
// Ledger: every microarch lever tested singly was null; the only monotone
// signal is thread count (32768 blk > 16384 > 8192). In the 1-load/thread
// geometry the serial preamble (perm load -> decode -> barrier) is the
// largest fraction of thread lifetime, so the duty-cycle fix should matter
// MOST here. x-loads are sequential (lane l -> float4 l of the row), so the
// wave-load is one 1KB burst independent of the permutation.

#define NSLOTS 16

typedef float fvec4 __attribute__((ext_vector_type(4)));

__device__ inline fvec4 lane_gather(fvec4 a, int byte_addr)
{
    fvec4 r;
    r.x = __int_as_float(__builtin_amdgcn_ds_bpermute(byte_addr, __float_as_int(a.x)));
    r.y = __int_as_float(__builtin_amdgcn_ds_bpermute(byte_addr, __float_as_int(a.y)));
    r.z = __int_as_float(__builtin_amdgcn_ds_bpermute(byte_addr, __float_as_int(a.z)));
    r.w = __int_as_float(__builtin_amdgcn_ds_bpermute(byte_addr, __float_as_int(a.w)));
    return r;
}

// Wave-cooperative one-hot decode: lane l holds float4 #l of a 16x16
// row-major perm matrix (row = l>>2, cols (l&3)*4..+3). Returns the hot
// column of row `slot` == perm[slot].
__device__ inline int decode_col(const fvec4 pr, int slot)
{
    int  h    = 0;
    bool pres = false;
    if (pr.x > 0.5f) { h = 0; pres = true; }
    if (pr.y > 0.5f) { h = 1; pres = true; }
    if (pr.z > 0.5f) { h = 2; pres = true; }
    if (pr.w > 0.5f) { h = 3; pres = true; }
    const unsigned long long bp = __ballot(pres);     // which lane(s) hold row's hot chunk
    const unsigned long long b0 = __ballot(h & 1);    // low bit of within-chunk idx
    const unsigned long long b1 = __ballot(h >> 1);   // high bit
    const int nib = (int)((bp >> (slot * 4)) & 0xFull);      // my row's 4 lanes
    const int cl  = slot * 4 + __builtin_ctz(nib);           // hot chunk's lane
    const int hh  = (int)((b0 >> cl) & 1ull) | ((int)((b1 >> cl) & 1ull) << 1);
    return ((cl & 3) << 2) | hh;                             // col in [0,16)
}

__global__ __launch_bounds__(256, 8) void permute_ws_kernel(
    const fvec4* __restrict__ x,
    const float* __restrict__ Ppos,
    const float* __restrict__ Pneg,
    fvec4* __restrict__ out,
    int total_v4)
{
    const int t    = threadIdx.x;
    const int lane = t & 63;
    const int i    = blockIdx.x * 256 + t;   // 1 float4 per thread

    // total_v4 is a multiple of 64 (whole rows), so this guard is
    // wave-uniform: ballots/bpermutes below always see all 64 lanes.
    if (i >= total_v4) return;

    // ---- x load FIRST: sequential, permutation-independent, cycle-0 issue ----
    const fvec4 a = x[i];

    // ---- decode overlaps the x-load latency (no LDS, no barrier) ----
    const fvec4 prp = ((const fvec4*)Ppos)[lane];   // 64 lanes x 16B = whole matrix
    const fvec4 prn = ((const fvec4*)Pneg)[lane];
    const int slot = lane >> 2;
    const int k4   = lane & 3;
    const int colp = decode_col(prp, slot);
    const int coln = decode_col(prn, slot);
    // source lane holding input float4 (4*col + k4); bpermute addr = lane*4
    const int bpa = (((colp << 2) | k4) << 2);
    const int bna = (((coln << 2) | k4) << 2);

    out[i] = lane_gather(a, bpa) - lane_gather(a, bna);
}

extern "C" void kernel_launch(void* const* d_in, const int* in_sizes, int n_in,
                              void* d_out, int out_size, void* d_ws, size_t ws_size,
                              hipStream_t stream)
{
    const fvec4* x    = (const fvec4*)d_in[0];
    const float* Ppos = (const float*)d_in[1];
    const float* Pneg = (const float*)d_in[2];
    fvec4*       out  = (fvec4*)d_out;

    const int total_v4 = out_size / 4;   // 33,554,432 / 4 = 8,388,608

    const int block = 256;
    const int grid  = (total_v4 + block - 1) / block;   // 32768, exact fit

    permute_ws_kernel<<<grid, block, 0, stream>>>(x, Ppos, Pneg, out, total_v4);
}